// Round 11
// baseline (406.419 us; speedup 1.0000x reference)
//
#include <hip/hip_runtime.h>
#include <hip/hip_bf16.h>
#include <math.h>

#define H 64
#define F 18
#define NPW 2      // nodes per wave in edge_gather (50k waves)
#define NBKT 1024  // max coarse buckets (LDS array size)
#define EPB 8192   // edges per block in count/place passes

typedef _Float16 f16x8 __attribute__((ext_vector_type(8)));
typedef _Float16 f16x4 __attribute__((ext_vector_type(4)));
typedef _Float16 f16x2 __attribute__((ext_vector_type(2)));
typedef float f32x4 __attribute__((ext_vector_type(4)));

// ---------------------------------------------------------------- embed ----
__global__ __launch_bounds__(256) void embed_kernel(
    const float* __restrict__ nf, const float* __restrict__ W,
    const float* __restrict__ b, _Float16* __restrict__ xh, int N)
{
    int n = blockIdx.x * 256 + threadIdx.x;
    if (n >= N) return;
    float acc[H];
#pragma unroll
    for (int j = 0; j < H; ++j) acc[j] = b[j];
    const float* f = nf + (long)n * F;
#pragma unroll
    for (int i = 0; i < F; ++i) {
        float c = f[i];
        const float* w = W + i * H;
#pragma unroll
        for (int j = 0; j < H; ++j) acc[j] += c * w[j];
    }
    union { uint4 v[8]; _Float16 h[64]; } O;
#pragma unroll
    for (int j = 0; j < H; ++j) O.h[j] = (_Float16)fmaxf(acc[j], 0.f);
    uint4* xo = (uint4*)(xh + (size_t)n * H);
#pragma unroll
    for (int i = 0; i < 8; ++i) xo[i] = O.v[i];
}

// -------------------------------------------- UV B-fragment prepack -------
__global__ __launch_bounds__(256) void packfrag_uv_kernel(
    const float* __restrict__ mW1, const float* __restrict__ aW1,
    f16x8* __restrict__ uvB)
{
    int t = blockIdx.x * 256 + threadIdx.x;  // 0..3071
    if (t >= 3072) return;
    int lane = t & 63;
    int frag = t >> 6;             // 0..47
    int l = frag / 24, rem = frag % 24;
    int side = rem / 12, q = rem % 12;
    int nt = q >> 1, kk = q & 1;
    int quad = lane >> 4, l15 = lane & 15;
    int col = nt * 16 + l15;
    f16x8 v;
#pragma unroll
    for (int j = 0; j < 8; ++j) {
        int k = side * 64 + kk * 32 + quad * 8 + j;
        float w = (col < 64) ? mW1[(size_t)l * 8192 + k * 64 + col]
                             : aW1[(size_t)l * 4096 + k * 32 + (col - 64)];
        v[j] = (_Float16)w;
    }
    uvB[(size_t)frag * 64 + lane] = v;
}

// ---------------------------------------------- update-path precompute ----
__global__ __launch_bounds__(256) void prep_update_kernel(
    const float* __restrict__ mW2, const float* __restrict__ mb2,
    const float* __restrict__ uW1,
    float* __restrict__ M2U, float* __restrict__ mbu)
{
    int t = blockIdx.x * 256 + threadIdx.x;  // 0..8191
    if (t >= 2 * 64 * 64) return;
    int l = t >> 12, r = t & 4095;
    int i = r >> 6, j = r & 63;
    const float* W2 = mW2 + (size_t)l * 4096;
    const float* U1b = uW1 + (size_t)l * 8192 + 4096;  // rows 64..127
    float s = 0.f;
    for (int k = 0; k < 64; ++k) s += W2[i * 64 + k] * U1b[k * 64 + j];
    M2U[t] = s;
    if (i == 0) {
        float sb = 0.f;
        const float* b2 = mb2 + (size_t)l * 64;
        for (int k = 0; k < 64; ++k) sb += b2[k] * U1b[k * 64 + j];
        mbu[l * 64 + j] = sb;
    }
}

// aggN stored in TRUE feature order.
__global__ __launch_bounds__(256) void packfrag_upd_kernel(
    const float* __restrict__ uW1, const float* __restrict__ M2U,
    const float* __restrict__ uW2, f16x8* __restrict__ updB)
{
    int t = blockIdx.x * 256 + threadIdx.x;  // 0..3071
    if (t >= 3072) return;
    int lane = t & 63;
    int frag = t >> 6;  // 0..47
    int l = frag / 24, f = frag % 24;
    int quad = lane >> 4, l15 = lane & 15;
    int g = f >> 3, ff = f & 7;
    int nt = ff >> 1, kk = ff & 1;
    const float* src;
    if (g == 0)      src = uW1 + (size_t)l * 8192;       // rows 0..63
    else if (g == 1) src = M2U + (size_t)l * 4096;
    else             src = uW2 + (size_t)l * 4096;
    f16x8 v;
#pragma unroll
    for (int j = 0; j < 8; ++j) {
        int k = kk * 32 + quad * 8 + j;
        v[j] = (_Float16)src[k * 64 + nt * 16 + l15];
    }
    updB[(size_t)frag * 64 + lane] = v;
}

// ----------------------------------------------- scan (M <= 256k) ---------
__global__ __launch_bounds__(256) void scan1_kernel(
    const int* __restrict__ deg, int* __restrict__ part,
    int* __restrict__ bsum, int N)
{
    __shared__ int lds[256];
    int t = threadIdx.x;
    int base = blockIdx.x * 1024 + t * 4;
    int v[4];
#pragma unroll
    for (int s = 0; s < 4; ++s) v[s] = (base + s < N) ? deg[base + s] : 0;
    int sum = v[0] + v[1] + v[2] + v[3];
    lds[t] = sum;
    __syncthreads();
    for (int off = 1; off < 256; off <<= 1) {
        int xv = (t >= off) ? lds[t - off] : 0;
        __syncthreads();
        lds[t] += xv;
        __syncthreads();
    }
    int excl = lds[t] - sum;
    if (t == 255) bsum[blockIdx.x] = lds[255];
    int p = excl;
#pragma unroll
    for (int s = 0; s < 4; ++s) {
        if (base + s < N) part[base + s] = p;
        p += v[s];
    }
}

__global__ __launch_bounds__(256) void scan2_kernel(int* __restrict__ bsum, int nb)
{
    __shared__ int lds[256];
    int t = threadIdx.x;
    int v = (t < nb) ? bsum[t] : 0;
    lds[t] = v;
    __syncthreads();
    for (int off = 1; off < 256; off <<= 1) {
        int xv = (t >= off) ? lds[t - off] : 0;
        __syncthreads();
        lds[t] += xv;
        __syncthreads();
    }
    if (t < nb) bsum[t] = lds[t] - v;
}

__global__ __launch_bounds__(256) void scan3_kernel(
    int* __restrict__ part, const int* __restrict__ bsum, int N)
{
    int i = blockIdx.x * 256 + threadIdx.x;
    if (i >= N) return;
    part[i] = part[i] + bsum[i >> 10];
}

// ----------------------------------------- coarse bucket partition --------
__global__ __launch_bounds__(256) void count_bucket_kernel(
    const int* __restrict__ col, int* __restrict__ cnt,
    unsigned int* __restrict__ serp, int E, int NB, int NBK, int BS)
{
    __shared__ int lc[NBKT];
    int t = threadIdx.x;
    if (blockIdx.x == 0 && t < 64) serp[t] = 0;   // fused serp init
    for (int i = t; i < NBK; i += 256) lc[i] = 0;
    __syncthreads();
    for (int s = 0; s < EPB / 256; ++s) {
        int e = blockIdx.x * EPB + s * 256 + t;
        if (e < E) atomicAdd(lc + (unsigned)col[e] / (unsigned)BS, 1);
    }
    __syncthreads();
    for (int i = t; i < NBK; i += 256)
        cnt[(size_t)i * NB + blockIdx.x] = lc[i];
}

// edata.x packs row | (local_col << 20)  (row < 2^20; local_col < BS <= 256)
__global__ __launch_bounds__(256) void place_kernel(
    const int* __restrict__ row, const int* __restrict__ col,
    const float* __restrict__ ew, const int* __restrict__ off,
    int2* __restrict__ edata, int E, int NB, int NBK, int BS)
{
    __shared__ int lc[NBKT];
    int t = threadIdx.x;
    for (int i = t; i < NBK; i += 256) lc[i] = 0;
    __syncthreads();
    for (int s = 0; s < EPB / 256; ++s) {
        int e = blockIdx.x * EPB + s * 256 + t;
        if (e < E) {
            int cv = col[e];
            int c = (unsigned)cv / (unsigned)BS;
            int lcol = cv - c * BS;
            int r = atomicAdd(lc + c, 1);
            int pos = off[(size_t)c * NB + blockIdx.x] + r;
            edata[pos] = make_int2(row[e] | (lcol << 20), __float_as_int(ew[e]));
        }
    }
}

// per-bucket in-place counting sort by local node; emits deg/startp.
__global__ __launch_bounds__(256) void bucket_sort_kernel(
    int2* __restrict__ edata, const int* __restrict__ off,
    int* __restrict__ deg, int* __restrict__ startp,
    int NB, int BS, int N, int E, int NBK)
{
    __shared__ int hist[256];
    __shared__ int psum[256];
    int b = blockIdx.x;
    int t = threadIdx.x;
    int base = off[(size_t)b * NB];
    int end  = (b + 1 < NBK) ? off[(size_t)(b + 1) * NB] : E;
    int cnt = end - base;
    int nlo = b * BS;

    hist[t] = 0;
    __syncthreads();

    int2 regs[8];
    int lnode[8];
#pragma unroll
    for (int ii = 0; ii < 8; ++ii) {
        int i = t + ii * 256;
        if (i < cnt) {
            regs[ii] = edata[base + i];
            lnode[ii] = ((unsigned)regs[ii].x) >> 20;
            atomicAdd(hist + lnode[ii], 1);   // no-return ds_add
        }
    }
    __syncthreads();

    int cv = hist[t];
    psum[t] = cv;
    __syncthreads();
    for (int o = 1; o < 256; o <<= 1) {
        int xv = (t >= o) ? psum[t - o] : 0;
        __syncthreads();
        psum[t] += xv;
        __syncthreads();
    }
    int excl = psum[t] - cv;
    int ng = nlo + t;
    if (t < BS && ng < N) {
        deg[ng] = cv;
        startp[ng] = base + excl;
    }
    hist[t] = excl;
    __syncthreads();

#pragma unroll
    for (int ii = 0; ii < 8; ++ii) {
        int i = t + ii * 256;
        if (i < cnt) {
            int pos = atomicAdd(hist + lnode[ii], 1);
            edata[base + pos] = make_int2(regs[ii].x & 0xFFFFF, regs[ii].y);
        }
    }
}

// -------------------------------------------------- per-node U/V GEMM -----
// Layer 0 only (layer 1's UV is produced fused in update_mfma).
__global__ __launch_bounds__(256) void uv_mfma_kernel(
    const _Float16* __restrict__ xh, const f16x8* __restrict__ Bf,  // [24][64]
    const float* __restrict__ mb1, const float* __restrict__ ab1,
    _Float16* __restrict__ UV, int N, int nbside)
{
    int bid = blockIdx.x;
    int side = (bid >= nbside) ? 1 : 0;
    int b = bid - side * nbside;
    int lane = threadIdx.x & 63;
    int wid = (b * 256 + (int)threadIdx.x) >> 6;
    int quad = lane >> 4, l15 = lane & 15;
    int nbase = wid * 64;
    if (nbase >= N) return;

    const f16x8* Bs = Bf + side * 12 * 64;
    f16x8 B[12];
#pragma unroll
    for (int i = 0; i < 12; ++i) B[i] = Bs[i * 64 + lane];
    float bv[6];
#pragma unroll
    for (int nt = 0; nt < 6; ++nt) {
        int col = nt * 16 + l15;
        bv[nt] = side ? 0.f : (col < 64 ? mb1[col] : ab1[col - 64]);
    }

    for (int mt = 0; mt < 4; ++mt) {
        int na = nbase + mt * 16 + l15;
        if (na >= N) na = N - 1;
        const f16x8* xrow = (const f16x8*)(xh + (size_t)na * H);
        f16x8 Ax[2];
        Ax[0] = xrow[quad];
        Ax[1] = xrow[4 + quad];

        f32x4 C[6];
#pragma unroll
        for (int nt = 0; nt < 6; ++nt) {
            f32x4 cc = {bv[nt], bv[nt], bv[nt], bv[nt]};
#pragma unroll
            for (int kk = 0; kk < 2; ++kk)
                cc = __builtin_amdgcn_mfma_f32_16x16x32_f16(Ax[kk], B[nt * 2 + kk], cc, 0, 0, 0);
            C[nt] = cc;
        }
#pragma unroll
        for (int r = 0; r < 4; ++r) {
            int n = nbase + mt * 16 + quad * 4 + r;
            if (n < N) {
#pragma unroll
                for (int nt = 0; nt < 6; ++nt)
                    UV[(size_t)n * 192 + side * 96 + nt * 16 + l15] = (_Float16)C[nt][r];
            }
        }
    }
}

// ---------------------------------------------------------- edge gather ---
// R25b: instruction diet on the VALU-bound body (R24 counters: VALU 65-68%).
// (1) packed f16 pairs via union reinterpret (v_pk_add_f16/v_pk_max_f16);
// (2) sigmoid division -> v_rcp_f32; (3) NPW=2 for finer scheduling
// granularity. Depth-2 load pipeline kept from R24.
__global__ __launch_bounds__(256) void edge_gather_kernel(
    const _Float16* __restrict__ UV,   // [N][192]: U 0..95, V 96..191
    const int2* __restrict__ edata,    // CSR-sorted {row, ew}
    const int* __restrict__ startp, const int* __restrict__ deg,
    const float* __restrict__ aW2, const float* __restrict__ ab2,
    _Float16* __restrict__ aggN, float* __restrict__ snorm, int N)
{
    int wid = (blockIdx.x * 256 + threadIdx.x) >> 6;
    int lane = threadIdx.x & 63;
    int g = lane >> 3, s = lane & 7;
    int n0 = wid * NPW;
    if (n0 >= N) return;
    int n1 = n0 + NPW; if (n1 > N) n1 = N;

    float aw2v[4];
#pragma unroll
    for (int j = 0; j < 4; ++j) aw2v[j] = aW2[s * 4 + j];
    float ab2v = ab2[0];
    const f16x2 zer = {(_Float16)0, (_Float16)0};

    typedef union { f16x8 v; f16x2 p[4]; } u8p;
    typedef union { f16x4 v; f16x2 p[2]; } u4p;

    for (int n = n0; n < n1; ++n) {
        int e0 = startp[n];
        int d = deg[n];
        int iters = (d + 7) >> 3;
        const _Float16* vrow = UV + (size_t)n * 192 + 96;
        u8p vm; vm.v = *(const f16x8*)(vrow + s * 8);
        u4p va; va.v = *(const f16x4*)(vrow + 64 + s * 4);

        float acc[8];
#pragma unroll
        for (int j = 0; j < 8; ++j) acc[j] = 0.f;
        float rfw = 0.f;

        if (iters > 0) {
            int2 ed0, ed1 = {0, 0}, ed2 = {0, 0};
            u8p um0;
            u4p ua0;
            {
                int ei = g;
                ed0 = edata[e0 + (ei < d ? ei : 0)];
                const _Float16* ur = UV + (size_t)ed0.x * 192;
                um0.v = *(const f16x8*)(ur + s * 8);
                ua0.v = *(const f16x4*)(ur + 64 + s * 4);
            }
            if (iters > 1) {
                int ei = 8 + g;
                ed1 = edata[e0 + (ei < d ? ei : 0)];
            }
            for (int it = 0; it < iters; ++it) {
                // ---- issue it+1's U-row load and it+2's edata load ----
                u8p umn = um0;
                u4p uan = ua0;
                if (it + 1 < iters) {
                    const _Float16* ur = UV + (size_t)ed1.x * 192;
                    umn.v = *(const f16x8*)(ur + s * 8);
                    uan.v = *(const f16x4*)(ur + 64 + s * 4);
                }
                if (it + 2 < iters) {
                    int ei = (it + 2) * 8 + g;
                    ed2 = edata[e0 + (ei < d ? ei : 0)];
                }

                // ---- compute edge it (data in ed0/um0/ua0) ----
                int ei = it * 8 + g;
                float ew = (ei < d) ? __int_as_float(ed0.y) : 0.f;
                // attention dot: packed relu(Ua+Va) then mix-fma
                f16x2 za0 = __builtin_elementwise_max(ua0.p[0] + va.p[0], zer);
                f16x2 za1 = __builtin_elementwise_max(ua0.p[1] + va.p[1], zer);
                float pp = (float)za0[0] * aw2v[0] + (float)za0[1] * aw2v[1]
                         + (float)za1[0] * aw2v[2] + (float)za1[1] * aw2v[3];
                pp += __shfl_xor(pp, 1);
                pp += __shfl_xor(pp, 2);
                pp += __shfl_xor(pp, 4);
                float fw = ew * __builtin_amdgcn_rcpf(1.f + __expf(-(pp + ab2v)));
                // main: packed relu(Um+Vm), mix-fma accumulate
#pragma unroll
                for (int j = 0; j < 4; ++j) {
                    f16x2 z = __builtin_elementwise_max(um0.p[j] + vm.p[j], zer);
                    acc[2 * j]     += (float)z[0] * fw;
                    acc[2 * j + 1] += (float)z[1] * fw;
                }
                rfw += fw;

                ed0 = ed1; ed1 = ed2; um0 = umn; ua0 = uan;
            }
        }

        // cross-group reduce (groups = lane bits 3..5)
#pragma unroll
        for (int o = 8; o <= 32; o <<= 1) {
#pragma unroll
            for (int j = 0; j < 8; ++j) acc[j] += __shfl_xor(acc[j], o);
            rfw += __shfl_xor(rfw, o);
        }
        float inv = 1.f / fmaxf(rfw, 1e-6f);
        if (g == 0) {
            union { _Float16 h[8]; uint4 v; } O;
#pragma unroll
            for (int j = 0; j < 8; ++j) O.h[j] = (_Float16)(acc[j] * inv);
            *(uint4*)(aggN + (size_t)n * H + s * 8) = O.v;
        }
        if (lane == 0) snorm[n] = rfw * inv;
    }
}

// --------------------------------------------------------------- update ----
// Fused epilogues: uvBn != null -> produce next layer's UV; doMax -> fused
// feature-max with 4 atomicMax per wave.
__global__ __launch_bounds__(256, 2) void update_mfma_kernel(
    _Float16* __restrict__ xh, const _Float16* __restrict__ agg,
    const float* __restrict__ snorm,
    const f16x8* __restrict__ Bfrag,  // [24][64] this layer
    const float* __restrict__ mbu,    // [64]
    const float* __restrict__ ub1, const float* __restrict__ ub2,
    const f16x8* __restrict__ uvBn,   // [24][64] next layer or null
    const float* __restrict__ mb1n, const float* __restrict__ ab1n,
    _Float16* __restrict__ UV,        // out if uvBn
    unsigned int* __restrict__ serp,  // out if doMax
    int N, int doMax)
{
    __shared__ __align__(16) _Float16 hlds[4][16 * 80];
    int wib = threadIdx.x >> 6;
    int lane = threadIdx.x & 63;
    int wid = (blockIdx.x * 256 + threadIdx.x) >> 6;
    int quad = lane >> 4, l15 = lane & 15;
    int nbase = wid * 64;
    if (nbase >= N) return;

    f16x8 Bu[8], Bm[8], Bw[8];
#pragma unroll
    for (int i = 0; i < 8; ++i) {
        Bu[i] = Bfrag[i * 64 + lane];
        Bm[i] = Bfrag[(8 + i) * 64 + lane];
        Bw[i] = Bfrag[(16 + i) * 64 + lane];
    }
    float mbuv[4], b1v[4], b2v[4];
#pragma unroll
    for (int nt = 0; nt < 4; ++nt) {
        mbuv[nt] = mbu[nt * 16 + l15];
        b1v[nt] = ub1[nt * 16 + l15];
        b2v[nt] = ub2[nt * 16 + l15];
    }
    float bvn[12];
    if (uvBn) {
#pragma unroll
        for (int q = 0; q < 12; ++q) {
            int sd = q / 6, nt2 = q % 6;
            int col = nt2 * 16 + l15;
            bvn[q] = sd ? 0.f : (col < 64 ? mb1n[col] : ab1n[col - 64]);
        }
    }
    float lmax[4] = {0.f, 0.f, 0.f, 0.f};

    for (int mt = 0; mt < 4; ++mt) {
        int na = nbase + mt * 16 + l15;
        if (na >= N) na = N - 1;
        const f16x8* xrow = (const f16x8*)(xh + (size_t)na * H);
        f16x8 Ax[2];
        Ax[0] = xrow[quad];
        Ax[1] = xrow[4 + quad];
        const f16x8* arow = (const f16x8*)(agg + (size_t)na * H);
        f16x8 Aa[2];
        Aa[0] = arow[quad];
        Aa[1] = arow[4 + quad];

        f32x4 Cx[4], Ca[4];
#pragma unroll
        for (int nt = 0; nt < 4; ++nt) {
            f32x4 cx = {0.f, 0.f, 0.f, 0.f}, ca = {0.f, 0.f, 0.f, 0.f};
#pragma unroll
            for (int kk = 0; kk < 2; ++kk) {
                cx = __builtin_amdgcn_mfma_f32_16x16x32_f16(Ax[kk], Bu[nt * 2 + kk], cx, 0, 0, 0);
                ca = __builtin_amdgcn_mfma_f32_16x16x32_f16(Aa[kk], Bm[nt * 2 + kk], ca, 0, 0, 0);
            }
            Cx[nt] = cx; Ca[nt] = ca;
        }

        int noder = nbase + mt * 16 + quad * 4;
        float sn_r[4];
#pragma unroll
        for (int r = 0; r < 4; ++r) {
            int ng = noder + r; if (ng >= N) ng = N - 1;
            sn_r[r] = snorm[ng];
        }

#pragma unroll
        for (int nt = 0; nt < 4; ++nt) {
#pragma unroll
            for (int r = 0; r < 4; ++r) {
                float hv = fmaxf(Cx[nt][r] + Ca[nt][r]
                                 + sn_r[r] * mbuv[nt] + b1v[nt], 0.f);
                hlds[wib][(quad * 4 + r) * 80 + nt * 16 + l15] = (_Float16)hv;
            }
        }
        __asm__ __volatile__("s_waitcnt lgkmcnt(0)" ::: "memory");
        f16x8 Ah[2];
        Ah[0] = *(const f16x8*)&hlds[wib][l15 * 80 + quad * 8];
        Ah[1] = *(const f16x8*)&hlds[wib][l15 * 80 + 32 + quad * 8];
        __asm__ __volatile__("s_waitcnt lgkmcnt(0)" ::: "memory");

        f32x4 C2[4];
#pragma unroll
        for (int nt = 0; nt < 4; ++nt) {
            f32x4 cc = {0.f, 0.f, 0.f, 0.f};
#pragma unroll
            for (int kk = 0; kk < 2; ++kk)
                cc = __builtin_amdgcn_mfma_f32_16x16x32_f16(Ah[kk], Bw[nt * 2 + kk], cc, 0, 0, 0);
            C2[nt] = cc;
        }

        // ---- xnew + xh write (+ local max) ----
        float xn[4][4];
#pragma unroll
        for (int r = 0; r < 4; ++r) {
            int ng = noder + r;
            if (ng < N) {
#pragma unroll
                for (int nt = 0; nt < 4; ++nt) {
                    size_t idx = (size_t)ng * H + nt * 16 + l15;
                    float xo = (float)xh[idx];
                    float v = fmaxf(C2[nt][r] + b2v[nt] + xo, 0.f);
                    xn[nt][r] = v;
                    xh[idx] = (_Float16)v;
                }
            } else {
#pragma unroll
                for (int nt = 0; nt < 4; ++nt) xn[nt][r] = 0.f;
            }
        }
        if (doMax) {
#pragma unroll
            for (int nt = 0; nt < 4; ++nt)
#pragma unroll
                for (int r = 0; r < 4; ++r) lmax[nt] = fmaxf(lmax[nt], xn[nt][r]);
        }

        // ---- fused UV production for next layer ----
        if (uvBn) {
#pragma unroll
            for (int nt = 0; nt < 4; ++nt)
#pragma unroll
                for (int r = 0; r < 4; ++r)
                    hlds[wib][(quad * 4 + r) * 80 + nt * 16 + l15] = (_Float16)xn[nt][r];
            __asm__ __volatile__("s_waitcnt lgkmcnt(0)" ::: "memory");
            f16x8 A2[2];
            A2[0] = *(const f16x8*)&hlds[wib][l15 * 80 + quad * 8];
            A2[1] = *(const f16x8*)&hlds[wib][l15 * 80 + 32 + quad * 8];
            __asm__ __volatile__("s_waitcnt lgkmcnt(0)" ::: "memory");

#pragma unroll
            for (int q = 0; q < 12; ++q) {
                int sd = q / 6, nt2 = q % 6;
                f16x8 Ba = uvBn[(sd * 12 + nt2 * 2) * 64 + lane];
                f16x8 Bb = uvBn[(sd * 12 + nt2 * 2 + 1) * 64 + lane];
                f32x4 cc = {bvn[q], bvn[q], bvn[q], bvn[q]};
                cc = __builtin_amdgcn_mfma_f32_16x16x32_f16(A2[0], Ba, cc, 0, 0, 0);
                cc = __builtin_amdgcn_mfma_f32_16x16x32_f16(A2[1], Bb, cc, 0, 0, 0);
#pragma unroll
                for (int r = 0; r < 4; ++r) {
                    int n = noder + r;
                    if (n < N)
                        UV[(size_t)n * 192 + sd * 96 + nt2 * 16 + l15] = (_Float16)cc[r];
                }
            }
        }
    }

    if (doMax) {
#pragma unroll
        for (int nt = 0; nt < 4; ++nt) {
            float m = lmax[nt];
            m = fmaxf(m, __shfl_xor(m, 16));
            m = fmaxf(m, __shfl_xor(m, 32));
            if (quad == 0) atomicMax(serp + nt * 16 + l15, __float_as_uint(m));
        }
    }
}

// ----------------------------------------------------------------- head ----
__global__ void head_kernel(const unsigned int* __restrict__ serp,
                            const float* __restrict__ hW,
                            const float* __restrict__ hb,
                            float* __restrict__ out)
{
    int j = threadIdx.x;  // 64 threads = 1 wave
    float v = __uint_as_float(serp[j]) * hW[j];
#pragma unroll
    for (int off = 32; off > 0; off >>= 1) v += __shfl_down(v, off);
    if (j == 0) out[0] = v + hb[0];
}

// --------------------------------------------------------------- launch ----
extern "C" void kernel_launch(void* const* d_in, const int* in_sizes, int n_in,
                              void* d_out, int out_size, void* d_ws, size_t ws_size,
                              hipStream_t stream)
{
    const float* nf  = (const float*)d_in[0];
    const int*   ei  = (const int*)d_in[1];
    const float* ew  = (const float*)d_in[2];
    const float* eW  = (const float*)d_in[3];
    const float* eb_ = (const float*)d_in[4];
    const float* mW1 = (const float*)d_in[5];
    const float* mb1 = (const float*)d_in[6];
    const float* mW2 = (const float*)d_in[7];
    const float* mb2 = (const float*)d_in[8];
    const float* aW1 = (const float*)d_in[9];
    const float* ab1 = (const float*)d_in[10];
    const float* aW2 = (const float*)d_in[11];
    const float* ab2 = (const float*)d_in[12];
    const float* uW1 = (const float*)d_in[13];
    const float* ub1 = (const float*)d_in[14];
    const float* uW2 = (const float*)d_in[15];
    const float* ub2 = (const float*)d_in[16];
    const float* hW  = (const float*)d_in[17];
    const float* hb  = (const float*)d_in[18];

    int N = in_sizes[0] / F;
    int E = in_sizes[2];
    const int* row = ei;
    const int* col = ei + E;

    size_t Nr = ((size_t)N + 3) & ~(size_t)3;
    size_t Er = ((size_t)E + 3) & ~(size_t)3;

    int BS  = (N + NBKT - 1) / NBKT;       // nodes per bucket (<=256)
    int NBK = (N + BS - 1) / BS;           // actual buckets (<=NBKT)
    int NB  = (E + EPB - 1) / EPB;         // blocks in count/place
    size_t M  = (size_t)NBK * NB;
    size_t Mr = (M + 3) & ~(size_t)3;

    _Float16* xh   = (_Float16*)d_ws;                 // Nr*64 f16
    _Float16* aggN = xh + Nr * 64;                    // Nr*64 f16
    float* snorm   = (float*)(aggN + Nr * 64);        // Nr
    unsigned int* serp = (unsigned int*)(snorm + Nr); // 64
    int* deg       = (int*)(serp + 64);               // Nr
    int* startp    = deg + Nr;                        // Nr
    int* bsum      = startp + Nr;                     // 256
    float* M2U     = (float*)(bsum + 256);            // 8192
    float* mbu     = M2U + 8192;                      // 128
    f16x8* updB    = (f16x8*)(mbu + 128);             // 3072 units
    f16x8* uvB     = updB + 3072;                     // 3072 units
    _Float16* UV   = (_Float16*)(uvB + 3072);         // Nr*192
    int* cnt       = (int*)(UV + Nr * 192);           // Mr
    int* off       = cnt + Mr;                        // Mr
    int2* edata    = (int2*)(off + Mr);               // Er

    int nb_n = (N + 255) / 256;
    int nbA = (int)((M + 1023) / 1024);               // <=256

    count_bucket_kernel<<<NB, 256, 0, stream>>>(col, cnt, serp, E, NB, NBK, BS);
    scan1_kernel<<<nbA, 256, 0, stream>>>(cnt, off, bsum, (int)M);
    scan2_kernel<<<1, 256, 0, stream>>>(bsum, nbA);
    scan3_kernel<<<(int)((M + 255) / 256), 256, 0, stream>>>(off, bsum, (int)M);
    place_kernel<<<NB, 256, 0, stream>>>(row, col, ew, off, edata, E, NB, NBK, BS);
    bucket_sort_kernel<<<NBK, 256, 0, stream>>>(edata, off, deg, startp,
                                                NB, BS, N, E, NBK);

    packfrag_uv_kernel<<<12, 256, 0, stream>>>(mW1, aW1, uvB);
    prep_update_kernel<<<32, 256, 0, stream>>>(mW2, mb2, uW1, M2U, mbu);
    packfrag_upd_kernel<<<12, 256, 0, stream>>>(uW1, M2U, uW2, updB);
    embed_kernel<<<nb_n, 256, 0, stream>>>(nf, eW, eb_, xh, N);

    int nwaves_n = (N + 63) / 64;
    int nb_uv = (N + 255) / 256;
    int nb_eg = (N + NPW * 4 - 1) / (NPW * 4);
    int nb_up = (nwaves_n + 3) / 4;

    // layer 0 UV from embed output
    uv_mfma_kernel<<<2 * nb_uv, 256, 0, stream>>>(
        xh, uvB, mb1, ab1, UV, N, nb_uv);
    edge_gather_kernel<<<nb_eg, 256, 0, stream>>>(
        UV, edata, startp, deg, aW2, ab2, aggN, snorm, N);
    // layer-0 update, fused production of layer-1 UV
    update_mfma_kernel<<<nb_up, 256, 0, stream>>>(
        xh, aggN, snorm, updB, mbu, ub1, ub2,
        uvB + 24 * 64, mb1 + H, ab1 + (H / 2), UV, nullptr, N, 0);
    edge_gather_kernel<<<nb_eg, 256, 0, stream>>>(
        UV, edata, startp, deg, aW2 + (H / 2), ab2 + 1, aggN, snorm, N);
    // layer-1 update, fused feature-max
    update_mfma_kernel<<<nb_up, 256, 0, stream>>>(
        xh, aggN, snorm, updB + 24 * 64, mbu + 64, ub1 + H, ub2 + H,
        nullptr, nullptr, nullptr, nullptr, serp, N, 1);

    head_kernel<<<1, 64, 0, stream>>>(serp, hW, hb, (float*)d_out);
}

// Round 12
// 389.841 us; speedup vs baseline: 1.0425x; 1.0425x over previous
//
#include <hip/hip_runtime.h>
#include <hip/hip_bf16.h>
#include <math.h>

#define H 64
#define F 18
#define NPW 2      // nodes per wave in edge_gather (50k waves)
#define NBKT 1024  // max coarse buckets (LDS array size)
#define EPB 8192   // edges per block in count/place passes

typedef _Float16 f16x8 __attribute__((ext_vector_type(8)));
typedef _Float16 f16x4 __attribute__((ext_vector_type(4)));
typedef _Float16 f16x2 __attribute__((ext_vector_type(2)));
typedef __fp16 h16x2 __attribute__((ext_vector_type(2)));
typedef float f32x4 __attribute__((ext_vector_type(4)));

// ---------------------------------------------------------------- embed ----
__global__ __launch_bounds__(256) void embed_kernel(
    const float* __restrict__ nf, const float* __restrict__ W,
    const float* __restrict__ b, _Float16* __restrict__ xh, int N)
{
    int n = blockIdx.x * 256 + threadIdx.x;
    if (n >= N) return;
    float acc[H];
#pragma unroll
    for (int j = 0; j < H; ++j) acc[j] = b[j];
    const float* f = nf + (long)n * F;
#pragma unroll
    for (int i = 0; i < F; ++i) {
        float c = f[i];
        const float* w = W + i * H;
#pragma unroll
        for (int j = 0; j < H; ++j) acc[j] += c * w[j];
    }
    union { uint4 v[8]; _Float16 h[64]; } O;
#pragma unroll
    for (int j = 0; j < H; ++j) O.h[j] = (_Float16)fmaxf(acc[j], 0.f);
    uint4* xo = (uint4*)(xh + (size_t)n * H);
#pragma unroll
    for (int i = 0; i < 8; ++i) xo[i] = O.v[i];
}

// -------------------------------------------- UV B-fragment prepack -------
__global__ __launch_bounds__(256) void packfrag_uv_kernel(
    const float* __restrict__ mW1, const float* __restrict__ aW1,
    f16x8* __restrict__ uvB)
{
    int t = blockIdx.x * 256 + threadIdx.x;  // 0..3071
    if (t >= 3072) return;
    int lane = t & 63;
    int frag = t >> 6;             // 0..47
    int l = frag / 24, rem = frag % 24;
    int side = rem / 12, q = rem % 12;
    int nt = q >> 1, kk = q & 1;
    int quad = lane >> 4, l15 = lane & 15;
    int col = nt * 16 + l15;
    f16x8 v;
#pragma unroll
    for (int j = 0; j < 8; ++j) {
        int k = side * 64 + kk * 32 + quad * 8 + j;
        float w = (col < 64) ? mW1[(size_t)l * 8192 + k * 64 + col]
                             : aW1[(size_t)l * 4096 + k * 32 + (col - 64)];
        v[j] = (_Float16)w;
    }
    uvB[(size_t)frag * 64 + lane] = v;
}

// ---------------------------------------------- update-path precompute ----
__global__ __launch_bounds__(256) void prep_update_kernel(
    const float* __restrict__ mW2, const float* __restrict__ mb2,
    const float* __restrict__ uW1,
    float* __restrict__ M2U, float* __restrict__ mbu)
{
    int t = blockIdx.x * 256 + threadIdx.x;  // 0..8191
    if (t >= 2 * 64 * 64) return;
    int l = t >> 12, r = t & 4095;
    int i = r >> 6, j = r & 63;
    const float* W2 = mW2 + (size_t)l * 4096;
    const float* U1b = uW1 + (size_t)l * 8192 + 4096;  // rows 64..127
    float s = 0.f;
    for (int k = 0; k < 64; ++k) s += W2[i * 64 + k] * U1b[k * 64 + j];
    M2U[t] = s;
    if (i == 0) {
        float sb = 0.f;
        const float* b2 = mb2 + (size_t)l * 64;
        for (int k = 0; k < 64; ++k) sb += b2[k] * U1b[k * 64 + j];
        mbu[l * 64 + j] = sb;
    }
}

// aggN stored in TRUE feature order.
__global__ __launch_bounds__(256) void packfrag_upd_kernel(
    const float* __restrict__ uW1, const float* __restrict__ M2U,
    const float* __restrict__ uW2, f16x8* __restrict__ updB)
{
    int t = blockIdx.x * 256 + threadIdx.x;  // 0..3071
    if (t >= 3072) return;
    int lane = t & 63;
    int frag = t >> 6;  // 0..47
    int l = frag / 24, f = frag % 24;
    int quad = lane >> 4, l15 = lane & 15;
    int g = f >> 3, ff = f & 7;
    int nt = ff >> 1, kk = ff & 1;
    const float* src;
    if (g == 0)      src = uW1 + (size_t)l * 8192;       // rows 0..63
    else if (g == 1) src = M2U + (size_t)l * 4096;
    else             src = uW2 + (size_t)l * 4096;
    f16x8 v;
#pragma unroll
    for (int j = 0; j < 8; ++j) {
        int k = kk * 32 + quad * 8 + j;
        v[j] = (_Float16)src[k * 64 + nt * 16 + l15];
    }
    updB[(size_t)frag * 64 + lane] = v;
}

// ----------------------------------------------- scan (M <= 256k) ---------
__global__ __launch_bounds__(256) void scan1_kernel(
    const int* __restrict__ deg, int* __restrict__ part,
    int* __restrict__ bsum, int N)
{
    __shared__ int lds[256];
    int t = threadIdx.x;
    int base = blockIdx.x * 1024 + t * 4;
    int v[4];
#pragma unroll
    for (int s = 0; s < 4; ++s) v[s] = (base + s < N) ? deg[base + s] : 0;
    int sum = v[0] + v[1] + v[2] + v[3];
    lds[t] = sum;
    __syncthreads();
    for (int off = 1; off < 256; off <<= 1) {
        int xv = (t >= off) ? lds[t - off] : 0;
        __syncthreads();
        lds[t] += xv;
        __syncthreads();
    }
    int excl = lds[t] - sum;
    if (t == 255) bsum[blockIdx.x] = lds[255];
    int p = excl;
#pragma unroll
    for (int s = 0; s < 4; ++s) {
        if (base + s < N) part[base + s] = p;
        p += v[s];
    }
}

__global__ __launch_bounds__(256) void scan2_kernel(int* __restrict__ bsum, int nb)
{
    __shared__ int lds[256];
    int t = threadIdx.x;
    int v = (t < nb) ? bsum[t] : 0;
    lds[t] = v;
    __syncthreads();
    for (int off = 1; off < 256; off <<= 1) {
        int xv = (t >= off) ? lds[t - off] : 0;
        __syncthreads();
        lds[t] += xv;
        __syncthreads();
    }
    if (t < nb) bsum[t] = lds[t] - v;
}

__global__ __launch_bounds__(256) void scan3_kernel(
    int* __restrict__ part, const int* __restrict__ bsum, int N)
{
    int i = blockIdx.x * 256 + threadIdx.x;
    if (i >= N) return;
    part[i] = part[i] + bsum[i >> 10];
}

// ----------------------------------------- coarse bucket partition --------
__global__ __launch_bounds__(256) void count_bucket_kernel(
    const int* __restrict__ col, int* __restrict__ cnt,
    unsigned int* __restrict__ serp, int E, int NB, int NBK, int BS)
{
    __shared__ int lc[NBKT];
    int t = threadIdx.x;
    if (blockIdx.x == 0 && t < 64) serp[t] = 0;   // fused serp init
    for (int i = t; i < NBK; i += 256) lc[i] = 0;
    __syncthreads();
    for (int s = 0; s < EPB / 256; ++s) {
        int e = blockIdx.x * EPB + s * 256 + t;
        if (e < E) atomicAdd(lc + (unsigned)col[e] / (unsigned)BS, 1);
    }
    __syncthreads();
    for (int i = t; i < NBK; i += 256)
        cnt[(size_t)i * NB + blockIdx.x] = lc[i];
}

// edata.x packs row | (local_col << 20)  (row < 2^20; local_col < BS <= 256)
__global__ __launch_bounds__(256) void place_kernel(
    const int* __restrict__ row, const int* __restrict__ col,
    const float* __restrict__ ew, const int* __restrict__ off,
    int2* __restrict__ edata, int E, int NB, int NBK, int BS)
{
    __shared__ int lc[NBKT];
    int t = threadIdx.x;
    for (int i = t; i < NBK; i += 256) lc[i] = 0;
    __syncthreads();
    for (int s = 0; s < EPB / 256; ++s) {
        int e = blockIdx.x * EPB + s * 256 + t;
        if (e < E) {
            int cv = col[e];
            int c = (unsigned)cv / (unsigned)BS;
            int lcol = cv - c * BS;
            int r = atomicAdd(lc + c, 1);
            int pos = off[(size_t)c * NB + blockIdx.x] + r;
            edata[pos] = make_int2(row[e] | (lcol << 20), __float_as_int(ew[e]));
        }
    }
}

// per-bucket in-place counting sort by local node; emits deg/startp.
__global__ __launch_bounds__(256) void bucket_sort_kernel(
    int2* __restrict__ edata, const int* __restrict__ off,
    int* __restrict__ deg, int* __restrict__ startp,
    int NB, int BS, int N, int E, int NBK)
{
    __shared__ int hist[256];
    __shared__ int psum[256];
    int b = blockIdx.x;
    int t = threadIdx.x;
    int base = off[(size_t)b * NB];
    int end  = (b + 1 < NBK) ? off[(size_t)(b + 1) * NB] : E;
    int cnt = end - base;
    int nlo = b * BS;

    hist[t] = 0;
    __syncthreads();

    int2 regs[8];
    int lnode[8];
#pragma unroll
    for (int ii = 0; ii < 8; ++ii) {
        int i = t + ii * 256;
        if (i < cnt) {
            regs[ii] = edata[base + i];
            lnode[ii] = ((unsigned)regs[ii].x) >> 20;
            atomicAdd(hist + lnode[ii], 1);   // no-return ds_add
        }
    }
    __syncthreads();

    int cv = hist[t];
    psum[t] = cv;
    __syncthreads();
    for (int o = 1; o < 256; o <<= 1) {
        int xv = (t >= o) ? psum[t - o] : 0;
        __syncthreads();
        psum[t] += xv;
        __syncthreads();
    }
    int excl = psum[t] - cv;
    int ng = nlo + t;
    if (t < BS && ng < N) {
        deg[ng] = cv;
        startp[ng] = base + excl;
    }
    hist[t] = excl;
    __syncthreads();

#pragma unroll
    for (int ii = 0; ii < 8; ++ii) {
        int i = t + ii * 256;
        if (i < cnt) {
            int pos = atomicAdd(hist + lnode[ii], 1);
            edata[base + pos] = make_int2(regs[ii].x & 0xFFFFF, regs[ii].y);
        }
    }
}

// -------------------------------------------------- per-node U/V GEMM -----
// Layer 0 only (layer 1's UV is produced fused in update_mfma).
__global__ __launch_bounds__(256) void uv_mfma_kernel(
    const _Float16* __restrict__ xh, const f16x8* __restrict__ Bf,  // [24][64]
    const float* __restrict__ mb1, const float* __restrict__ ab1,
    _Float16* __restrict__ UV, int N, int nbside)
{
    int bid = blockIdx.x;
    int side = (bid >= nbside) ? 1 : 0;
    int b = bid - side * nbside;
    int lane = threadIdx.x & 63;
    int wid = (b * 256 + (int)threadIdx.x) >> 6;
    int quad = lane >> 4, l15 = lane & 15;
    int nbase = wid * 64;
    if (nbase >= N) return;

    const f16x8* Bs = Bf + side * 12 * 64;
    f16x8 B[12];
#pragma unroll
    for (int i = 0; i < 12; ++i) B[i] = Bs[i * 64 + lane];
    float bv[6];
#pragma unroll
    for (int nt = 0; nt < 6; ++nt) {
        int col = nt * 16 + l15;
        bv[nt] = side ? 0.f : (col < 64 ? mb1[col] : ab1[col - 64]);
    }

    for (int mt = 0; mt < 4; ++mt) {
        int na = nbase + mt * 16 + l15;
        if (na >= N) na = N - 1;
        const f16x8* xrow = (const f16x8*)(xh + (size_t)na * H);
        f16x8 Ax[2];
        Ax[0] = xrow[quad];
        Ax[1] = xrow[4 + quad];

        f32x4 C[6];
#pragma unroll
        for (int nt = 0; nt < 6; ++nt) {
            f32x4 cc = {bv[nt], bv[nt], bv[nt], bv[nt]};
#pragma unroll
            for (int kk = 0; kk < 2; ++kk)
                cc = __builtin_amdgcn_mfma_f32_16x16x32_f16(Ax[kk], B[nt * 2 + kk], cc, 0, 0, 0);
            C[nt] = cc;
        }
#pragma unroll
        for (int r = 0; r < 4; ++r) {
            int n = nbase + mt * 16 + quad * 4 + r;
            if (n < N) {
#pragma unroll
                for (int nt = 0; nt < 6; ++nt)
                    UV[(size_t)n * 192 + side * 96 + nt * 16 + l15] = (_Float16)C[nt][r];
            }
        }
    }
}

// ---------------------------------------------------------- edge gather ---
// R26: (1) att dot via v_dot2_f32_f16 (fdot2, guarded); (2) pp reduce
// xor1/xor2 via quad_perm DPP (VALU pipe, removes 2 LDS bpermutes + their
// serial latency per edge-iter); xor4 stays as shfl. Depth-2 load pipeline
// + packed f16 math + rcp sigmoid kept from R25b.
__global__ __launch_bounds__(256) void edge_gather_kernel(
    const _Float16* __restrict__ UV,   // [N][192]: U 0..95, V 96..191
    const int2* __restrict__ edata,    // CSR-sorted {row, ew}
    const int* __restrict__ startp, const int* __restrict__ deg,
    const float* __restrict__ aW2, const float* __restrict__ ab2,
    _Float16* __restrict__ aggN, float* __restrict__ snorm, int N)
{
    int wid = (blockIdx.x * 256 + threadIdx.x) >> 6;
    int lane = threadIdx.x & 63;
    int g = lane >> 3, s = lane & 7;
    int n0 = wid * NPW;
    if (n0 >= N) return;
    int n1 = n0 + NPW; if (n1 > N) n1 = N;

    float aw2v[4];
#pragma unroll
    for (int j = 0; j < 4; ++j) aw2v[j] = aW2[s * 4 + j];
#if __has_builtin(__builtin_amdgcn_fdot2)
    h16x2 aw01, aw23;
    aw01[0] = (__fp16)aw2v[0]; aw01[1] = (__fp16)aw2v[1];
    aw23[0] = (__fp16)aw2v[2]; aw23[1] = (__fp16)aw2v[3];
#endif
    float ab2v = ab2[0];
    const f16x2 zer = {(_Float16)0, (_Float16)0};

    typedef union { f16x8 v; f16x2 p[4]; } u8p;
    typedef union { f16x4 v; f16x2 p[2]; h16x2 h[2]; } u4p;

    for (int n = n0; n < n1; ++n) {
        int e0 = startp[n];
        int d = deg[n];
        int iters = (d + 7) >> 3;
        const _Float16* vrow = UV + (size_t)n * 192 + 96;
        u8p vm; vm.v = *(const f16x8*)(vrow + s * 8);
        u4p va; va.v = *(const f16x4*)(vrow + 64 + s * 4);

        float acc[8];
#pragma unroll
        for (int j = 0; j < 8; ++j) acc[j] = 0.f;
        float rfw = 0.f;

        if (iters > 0) {
            int2 ed0, ed1 = {0, 0}, ed2 = {0, 0};
            u8p um0;
            u4p ua0;
            {
                int ei = g;
                ed0 = edata[e0 + (ei < d ? ei : 0)];
                const _Float16* ur = UV + (size_t)ed0.x * 192;
                um0.v = *(const f16x8*)(ur + s * 8);
                ua0.v = *(const f16x4*)(ur + 64 + s * 4);
            }
            if (iters > 1) {
                int ei = 8 + g;
                ed1 = edata[e0 + (ei < d ? ei : 0)];
            }
            for (int it = 0; it < iters; ++it) {
                // ---- issue it+1's U-row load and it+2's edata load ----
                u8p umn = um0;
                u4p uan = ua0;
                if (it + 1 < iters) {
                    const _Float16* ur = UV + (size_t)ed1.x * 192;
                    umn.v = *(const f16x8*)(ur + s * 8);
                    uan.v = *(const f16x4*)(ur + 64 + s * 4);
                }
                if (it + 2 < iters) {
                    int ei = (it + 2) * 8 + g;
                    ed2 = edata[e0 + (ei < d ? ei : 0)];
                }

                // ---- compute edge it (data in ed0/um0/ua0) ----
                int ei = it * 8 + g;
                float ew = (ei < d) ? __int_as_float(ed0.y) : 0.f;
                // attention dot: packed relu(Ua+Va) then dot2
                f16x2 za0 = __builtin_elementwise_max(ua0.p[0] + va.p[0], zer);
                f16x2 za1 = __builtin_elementwise_max(ua0.p[1] + va.p[1], zer);
#if __has_builtin(__builtin_amdgcn_fdot2)
                h16x2 hz0, hz1;
                __builtin_memcpy(&hz0, &za0, 4);
                __builtin_memcpy(&hz1, &za1, 4);
                float pp = __builtin_amdgcn_fdot2(
                    hz0, aw01,
                    __builtin_amdgcn_fdot2(hz1, aw23, 0.f, false), false);
#else
                float pp = (float)za0[0] * aw2v[0] + (float)za0[1] * aw2v[1]
                         + (float)za1[0] * aw2v[2] + (float)za1[1] * aw2v[3];
#endif
                // xor1/xor2 via quad_perm DPP (VALU pipe), xor4 via shfl
                pp += __int_as_float(__builtin_amdgcn_update_dpp(
                    0, __float_as_int(pp), 0xB1, 0xF, 0xF, true));
                pp += __int_as_float(__builtin_amdgcn_update_dpp(
                    0, __float_as_int(pp), 0x4E, 0xF, 0xF, true));
                pp += __shfl_xor(pp, 4);
                float fw = ew * __builtin_amdgcn_rcpf(1.f + __expf(-(pp + ab2v)));
                // main: packed relu(Um+Vm), mix-fma accumulate
#pragma unroll
                for (int j = 0; j < 4; ++j) {
                    f16x2 z = __builtin_elementwise_max(um0.p[j] + vm.p[j], zer);
                    acc[2 * j]     += (float)z[0] * fw;
                    acc[2 * j + 1] += (float)z[1] * fw;
                }
                rfw += fw;

                ed0 = ed1; ed1 = ed2; um0 = umn; ua0 = uan;
            }
        }

        // cross-group reduce (groups = lane bits 3..5)
#pragma unroll
        for (int o = 8; o <= 32; o <<= 1) {
#pragma unroll
            for (int j = 0; j < 8; ++j) acc[j] += __shfl_xor(acc[j], o);
            rfw += __shfl_xor(rfw, o);
        }
        float inv = 1.f / fmaxf(rfw, 1e-6f);
        if (g == 0) {
            union { _Float16 h[8]; uint4 v; } O;
#pragma unroll
            for (int j = 0; j < 8; ++j) O.h[j] = (_Float16)(acc[j] * inv);
            *(uint4*)(aggN + (size_t)n * H + s * 8) = O.v;
        }
        if (lane == 0) snorm[n] = rfw * inv;
    }
}

// --------------------------------------------------------------- update ----
// R26: 1-wave (64-thread) blocks — grid 391 -> 1563 blocks fixes the
// 1.53-blocks/CU makespan imbalance (same per-wave work, B-frag loads
// amortized identically over 4 mt-iters). Fused epilogues kept.
__global__ __launch_bounds__(64, 2) void update_mfma_kernel(
    _Float16* __restrict__ xh, const _Float16* __restrict__ agg,
    const float* __restrict__ snorm,
    const f16x8* __restrict__ Bfrag,  // [24][64] this layer
    const float* __restrict__ mbu,    // [64]
    const float* __restrict__ ub1, const float* __restrict__ ub2,
    const f16x8* __restrict__ uvBn,   // [24][64] next layer or null
    const float* __restrict__ mb1n, const float* __restrict__ ab1n,
    _Float16* __restrict__ UV,        // out if uvBn
    unsigned int* __restrict__ serp,  // out if doMax
    int N, int doMax)
{
    __shared__ __align__(16) _Float16 hlds[16 * 80];
    int lane = threadIdx.x;
    int wid = blockIdx.x;
    int quad = lane >> 4, l15 = lane & 15;
    int nbase = wid * 64;
    if (nbase >= N) return;

    f16x8 Bu[8], Bm[8], Bw[8];
#pragma unroll
    for (int i = 0; i < 8; ++i) {
        Bu[i] = Bfrag[i * 64 + lane];
        Bm[i] = Bfrag[(8 + i) * 64 + lane];
        Bw[i] = Bfrag[(16 + i) * 64 + lane];
    }
    float mbuv[4], b1v[4], b2v[4];
#pragma unroll
    for (int nt = 0; nt < 4; ++nt) {
        mbuv[nt] = mbu[nt * 16 + l15];
        b1v[nt] = ub1[nt * 16 + l15];
        b2v[nt] = ub2[nt * 16 + l15];
    }
    float bvn[12];
    if (uvBn) {
#pragma unroll
        for (int q = 0; q < 12; ++q) {
            int sd = q / 6, nt2 = q % 6;
            int col = nt2 * 16 + l15;
            bvn[q] = sd ? 0.f : (col < 64 ? mb1n[col] : ab1n[col - 64]);
        }
    }
    float lmax[4] = {0.f, 0.f, 0.f, 0.f};

    for (int mt = 0; mt < 4; ++mt) {
        int na = nbase + mt * 16 + l15;
        if (na >= N) na = N - 1;
        const f16x8* xrow = (const f16x8*)(xh + (size_t)na * H);
        f16x8 Ax[2];
        Ax[0] = xrow[quad];
        Ax[1] = xrow[4 + quad];
        const f16x8* arow = (const f16x8*)(agg + (size_t)na * H);
        f16x8 Aa[2];
        Aa[0] = arow[quad];
        Aa[1] = arow[4 + quad];

        f32x4 Cx[4], Ca[4];
#pragma unroll
        for (int nt = 0; nt < 4; ++nt) {
            f32x4 cx = {0.f, 0.f, 0.f, 0.f}, ca = {0.f, 0.f, 0.f, 0.f};
#pragma unroll
            for (int kk = 0; kk < 2; ++kk) {
                cx = __builtin_amdgcn_mfma_f32_16x16x32_f16(Ax[kk], Bu[nt * 2 + kk], cx, 0, 0, 0);
                ca = __builtin_amdgcn_mfma_f32_16x16x32_f16(Aa[kk], Bm[nt * 2 + kk], ca, 0, 0, 0);
            }
            Cx[nt] = cx; Ca[nt] = ca;
        }

        int noder = nbase + mt * 16 + quad * 4;
        float sn_r[4];
#pragma unroll
        for (int r = 0; r < 4; ++r) {
            int ng = noder + r; if (ng >= N) ng = N - 1;
            sn_r[r] = snorm[ng];
        }

#pragma unroll
        for (int nt = 0; nt < 4; ++nt) {
#pragma unroll
            for (int r = 0; r < 4; ++r) {
                float hv = fmaxf(Cx[nt][r] + Ca[nt][r]
                                 + sn_r[r] * mbuv[nt] + b1v[nt], 0.f);
                hlds[(quad * 4 + r) * 80 + nt * 16 + l15] = (_Float16)hv;
            }
        }
        __asm__ __volatile__("s_waitcnt lgkmcnt(0)" ::: "memory");
        f16x8 Ah[2];
        Ah[0] = *(const f16x8*)&hlds[l15 * 80 + quad * 8];
        Ah[1] = *(const f16x8*)&hlds[l15 * 80 + 32 + quad * 8];
        __asm__ __volatile__("s_waitcnt lgkmcnt(0)" ::: "memory");

        f32x4 C2[4];
#pragma unroll
        for (int nt = 0; nt < 4; ++nt) {
            f32x4 cc = {0.f, 0.f, 0.f, 0.f};
#pragma unroll
            for (int kk = 0; kk < 2; ++kk)
                cc = __builtin_amdgcn_mfma_f32_16x16x32_f16(Ah[kk], Bw[nt * 2 + kk], cc, 0, 0, 0);
            C2[nt] = cc;
        }

        // ---- xnew + xh write (+ local max) ----
        float xn[4][4];
#pragma unroll
        for (int r = 0; r < 4; ++r) {
            int ng = noder + r;
            if (ng < N) {
#pragma unroll
                for (int nt = 0; nt < 4; ++nt) {
                    size_t idx = (size_t)ng * H + nt * 16 + l15;
                    float xo = (float)xh[idx];
                    float v = fmaxf(C2[nt][r] + b2v[nt] + xo, 0.f);
                    xn[nt][r] = v;
                    xh[idx] = (_Float16)v;
                }
            } else {
#pragma unroll
                for (int nt = 0; nt < 4; ++nt) xn[nt][r] = 0.f;
            }
        }
        if (doMax) {
#pragma unroll
            for (int nt = 0; nt < 4; ++nt)
#pragma unroll
                for (int r = 0; r < 4; ++r) lmax[nt] = fmaxf(lmax[nt], xn[nt][r]);
        }

        // ---- fused UV production for next layer ----
        if (uvBn) {
#pragma unroll
            for (int nt = 0; nt < 4; ++nt)
#pragma unroll
                for (int r = 0; r < 4; ++r)
                    hlds[(quad * 4 + r) * 80 + nt * 16 + l15] = (_Float16)xn[nt][r];
            __asm__ __volatile__("s_waitcnt lgkmcnt(0)" ::: "memory");
            f16x8 A2[2];
            A2[0] = *(const f16x8*)&hlds[l15 * 80 + quad * 8];
            A2[1] = *(const f16x8*)&hlds[l15 * 80 + 32 + quad * 8];
            __asm__ __volatile__("s_waitcnt lgkmcnt(0)" ::: "memory");

#pragma unroll
            for (int q = 0; q < 12; ++q) {
                int sd = q / 6, nt2 = q % 6;
                f16x8 Ba = uvBn[(sd * 12 + nt2 * 2) * 64 + lane];
                f16x8 Bb = uvBn[(sd * 12 + nt2 * 2 + 1) * 64 + lane];
                f32x4 cc = {bvn[q], bvn[q], bvn[q], bvn[q]};
                cc = __builtin_amdgcn_mfma_f32_16x16x32_f16(A2[0], Ba, cc, 0, 0, 0);
                cc = __builtin_amdgcn_mfma_f32_16x16x32_f16(A2[1], Bb, cc, 0, 0, 0);
#pragma unroll
                for (int r = 0; r < 4; ++r) {
                    int n = noder + r;
                    if (n < N)
                        UV[(size_t)n * 192 + sd * 96 + nt2 * 16 + l15] = (_Float16)cc[r];
                }
            }
        }
    }

    if (doMax) {
#pragma unroll
        for (int nt = 0; nt < 4; ++nt) {
            float m = lmax[nt];
            m = fmaxf(m, __shfl_xor(m, 16));
            m = fmaxf(m, __shfl_xor(m, 32));
            if (quad == 0) atomicMax(serp + nt * 16 + l15, __float_as_uint(m));
        }
    }
}

// ----------------------------------------------------------------- head ----
__global__ void head_kernel(const unsigned int* __restrict__ serp,
                            const float* __restrict__ hW,
                            const float* __restrict__ hb,
                            float* __restrict__ out)
{
    int j = threadIdx.x;  // 64 threads = 1 wave
    float v = __uint_as_float(serp[j]) * hW[j];
#pragma unroll
    for (int off = 32; off > 0; off >>= 1) v += __shfl_down(v, off);
    if (j == 0) out[0] = v + hb[0];
}

// --------------------------------------------------------------- launch ----
extern "C" void kernel_launch(void* const* d_in, const int* in_sizes, int n_in,
                              void* d_out, int out_size, void* d_ws, size_t ws_size,
                              hipStream_t stream)
{
    const float* nf  = (const float*)d_in[0];
    const int*   ei  = (const int*)d_in[1];
    const float* ew  = (const float*)d_in[2];
    const float* eW  = (const float*)d_in[3];
    const float* eb_ = (const float*)d_in[4];
    const float* mW1 = (const float*)d_in[5];
    const float* mb1 = (const float*)d_in[6];
    const float* mW2 = (const float*)d_in[7];
    const float* mb2 = (const float*)d_in[8];
    const float* aW1 = (const float*)d_in[9];
    const float* ab1 = (const float*)d_in[10];
    const float* aW2 = (const float*)d_in[11];
    const float* ab2 = (const float*)d_in[12];
    const float* uW1 = (const float*)d_in[13];
    const float* ub1 = (const float*)d_in[14];
    const float* uW2 = (const float*)d_in[15];
    const float* ub2 = (const float*)d_in[16];
    const float* hW  = (const float*)d_in[17];
    const float* hb  = (const float*)d_in[18];

    int N = in_sizes[0] / F;
    int E = in_sizes[2];
    const int* row = ei;
    const int* col = ei + E;

    size_t Nr = ((size_t)N + 3) & ~(size_t)3;
    size_t Er = ((size_t)E + 3) & ~(size_t)3;

    int BS  = (N + NBKT - 1) / NBKT;       // nodes per bucket (<=256)
    int NBK = (N + BS - 1) / BS;           // actual buckets (<=NBKT)
    int NB  = (E + EPB - 1) / EPB;         // blocks in count/place
    size_t M  = (size_t)NBK * NB;
    size_t Mr = (M + 3) & ~(size_t)3;

    _Float16* xh   = (_Float16*)d_ws;                 // Nr*64 f16
    _Float16* aggN = xh + Nr * 64;                    // Nr*64 f16
    float* snorm   = (float*)(aggN + Nr * 64);        // Nr
    unsigned int* serp = (unsigned int*)(snorm + Nr); // 64
    int* deg       = (int*)(serp + 64);               // Nr
    int* startp    = deg + Nr;                        // Nr
    int* bsum      = startp + Nr;                     // 256
    float* M2U     = (float*)(bsum + 256);            // 8192
    float* mbu     = M2U + 8192;                      // 128
    f16x8* updB    = (f16x8*)(mbu + 128);             // 3072 units
    f16x8* uvB     = updB + 3072;                     // 3072 units
    _Float16* UV   = (_Float16*)(uvB + 3072);         // Nr*192
    int* cnt       = (int*)(UV + Nr * 192);           // Mr
    int* off       = cnt + Mr;                        // Mr
    int2* edata    = (int2*)(off + Mr);               // Er

    int nb_n = (N + 255) / 256;
    int nbA = (int)((M + 1023) / 1024);               // <=256

    count_bucket_kernel<<<NB, 256, 0, stream>>>(col, cnt, serp, E, NB, NBK, BS);
    scan1_kernel<<<nbA, 256, 0, stream>>>(cnt, off, bsum, (int)M);
    scan2_kernel<<<1, 256, 0, stream>>>(bsum, nbA);
    scan3_kernel<<<(int)((M + 255) / 256), 256, 0, stream>>>(off, bsum, (int)M);
    place_kernel<<<NB, 256, 0, stream>>>(row, col, ew, off, edata, E, NB, NBK, BS);
    bucket_sort_kernel<<<NBK, 256, 0, stream>>>(edata, off, deg, startp,
                                                NB, BS, N, E, NBK);

    packfrag_uv_kernel<<<12, 256, 0, stream>>>(mW1, aW1, uvB);
    prep_update_kernel<<<32, 256, 0, stream>>>(mW2, mb2, uW1, M2U, mbu);
    packfrag_upd_kernel<<<12, 256, 0, stream>>>(uW1, M2U, uW2, updB);
    embed_kernel<<<nb_n, 256, 0, stream>>>(nf, eW, eb_, xh, N);

    int nwaves_n = (N + 63) / 64;
    int nb_uv = (N + 255) / 256;
    int nb_eg = (N + NPW * 4 - 1) / (NPW * 4);

    // layer 0 UV from embed output
    uv_mfma_kernel<<<2 * nb_uv, 256, 0, stream>>>(
        xh, uvB, mb1, ab1, UV, N, nb_uv);
    edge_gather_kernel<<<nb_eg, 256, 0, stream>>>(
        UV, edata, startp, deg, aW2, ab2, aggN, snorm, N);
    // layer-0 update, fused production of layer-1 UV
    update_mfma_kernel<<<nwaves_n, 64, 0, stream>>>(
        xh, aggN, snorm, updB, mbu, ub1, ub2,
        uvB + 24 * 64, mb1 + H, ab1 + (H / 2), UV, nullptr, N, 0);
    edge_gather_kernel<<<nb_eg, 256, 0, stream>>>(
        UV, edata, startp, deg, aW2 + (H / 2), ab2 + 1, aggN, snorm, N);
    // layer-1 update, fused feature-max
    update_mfma_kernel<<<nwaves_n, 64, 0, stream>>>(
        xh, aggN, snorm, updB + 24 * 64, mbu + 64, ub1 + H, ub2 + H,
        nullptr, nullptr, nullptr, nullptr, serp, N, 1);

    head_kernel<<<1, 64, 0, stream>>>(serp, hW, hb, (float*)d_out);
}

// Round 13
// 368.466 us; speedup vs baseline: 1.1030x; 1.0580x over previous
//
#include <hip/hip_runtime.h>
#include <hip/hip_bf16.h>
#include <math.h>

#define H 64
#define F 18
#define NPW 2      // nodes per wave in edge_gather (50k waves)
#define NBKT 1024  // max coarse buckets (LDS array size)
#define EPB 8192   // edges per block in count/place passes

typedef _Float16 f16x8 __attribute__((ext_vector_type(8)));
typedef _Float16 f16x4 __attribute__((ext_vector_type(4)));
typedef _Float16 f16x2 __attribute__((ext_vector_type(2)));
typedef __fp16 h16x2 __attribute__((ext_vector_type(2)));
typedef float f32x4 __attribute__((ext_vector_type(4)));

// ---------------------------------------------- update-path precompute ----
__global__ __launch_bounds__(256) void prep_update_kernel(
    const float* __restrict__ mW2, const float* __restrict__ mb2,
    const float* __restrict__ uW1,
    float* __restrict__ M2U, float* __restrict__ mbu)
{
    int t = blockIdx.x * 256 + threadIdx.x;  // 0..8191
    if (t >= 2 * 64 * 64) return;
    int l = t >> 12, r = t & 4095;
    int i = r >> 6, j = r & 63;
    const float* W2 = mW2 + (size_t)l * 4096;
    const float* U1b = uW1 + (size_t)l * 8192 + 4096;  // rows 64..127
    float s = 0.f;
    for (int k = 0; k < 64; ++k) s += W2[i * 64 + k] * U1b[k * 64 + j];
    M2U[t] = s;
    if (i == 0) {
        float sb = 0.f;
        const float* b2 = mb2 + (size_t)l * 64;
        for (int k = 0; k < 64; ++k) sb += b2[k] * U1b[k * 64 + j];
        mbu[l * 64 + j] = sb;
    }
}

// --------------------------------- merged B-fragment prepack (uv/upd/emb) --
// frag 0..47: uv (l, side, nt, kk); 48..95: upd; 96..99: embB (K=32 padded).
__global__ __launch_bounds__(256) void packfrag_all_kernel(
    const float* __restrict__ mW1, const float* __restrict__ aW1,
    const float* __restrict__ uW1, const float* __restrict__ M2U,
    const float* __restrict__ uW2, const float* __restrict__ eW,
    f16x8* __restrict__ uvB, f16x8* __restrict__ updB,
    f16x8* __restrict__ embB)
{
    int t = blockIdx.x * 256 + threadIdx.x;  // 0..6399
    if (t >= 6400) return;
    int lane = t & 63;
    int frag = t >> 6;  // 0..99
    int quad = lane >> 4, l15 = lane & 15;
    if (frag < 48) {
        int l = frag / 24, rem = frag % 24;
        int side = rem / 12, q = rem % 12;
        int nt = q >> 1, kk = q & 1;
        int col = nt * 16 + l15;
        f16x8 v;
#pragma unroll
        for (int j = 0; j < 8; ++j) {
            int k = side * 64 + kk * 32 + quad * 8 + j;
            float w = (col < 64) ? mW1[(size_t)l * 8192 + k * 64 + col]
                                 : aW1[(size_t)l * 4096 + k * 32 + (col - 64)];
            v[j] = (_Float16)w;
        }
        uvB[(size_t)frag * 64 + lane] = v;
    } else if (frag < 96) {
        int f2 = frag - 48;
        int l = f2 / 24, f = f2 % 24;
        int g = f >> 3, ff = f & 7;
        int nt = ff >> 1, kk = ff & 1;
        const float* src;
        if (g == 0)      src = uW1 + (size_t)l * 8192;
        else if (g == 1) src = M2U + (size_t)l * 4096;
        else             src = uW2 + (size_t)l * 4096;
        f16x8 v;
#pragma unroll
        for (int j = 0; j < 8; ++j) {
            int k = kk * 32 + quad * 8 + j;
            v[j] = (_Float16)src[k * 64 + nt * 16 + l15];
        }
        updB[(size_t)f2 * 64 + lane] = v;
    } else {
        int nt = frag - 96;
        f16x8 v;
#pragma unroll
        for (int j = 0; j < 8; ++j) {
            int k = quad * 8 + j;
            v[j] = (k < F) ? (_Float16)eW[k * 64 + nt * 16 + l15] : (_Float16)0;
        }
        embB[(size_t)nt * 64 + lane] = v;
    }
}

// ----------------------------------------------- scan (M <= 256k) ---------
__global__ __launch_bounds__(256) void scan1_kernel(
    const int* __restrict__ deg, int* __restrict__ part,
    int* __restrict__ bsum, int N)
{
    __shared__ int lds[256];
    int t = threadIdx.x;
    int base = blockIdx.x * 1024 + t * 4;
    int v[4];
#pragma unroll
    for (int s = 0; s < 4; ++s) v[s] = (base + s < N) ? deg[base + s] : 0;
    int sum = v[0] + v[1] + v[2] + v[3];
    lds[t] = sum;
    __syncthreads();
    for (int off = 1; off < 256; off <<= 1) {
        int xv = (t >= off) ? lds[t - off] : 0;
        __syncthreads();
        lds[t] += xv;
        __syncthreads();
    }
    int excl = lds[t] - sum;
    if (t == 255) bsum[blockIdx.x] = lds[255];
    int p = excl;
#pragma unroll
    for (int s = 0; s < 4; ++s) {
        if (base + s < N) part[base + s] = p;
        p += v[s];
    }
}

__global__ __launch_bounds__(256) void scan2_kernel(int* __restrict__ bsum, int nb)
{
    __shared__ int lds[256];
    int t = threadIdx.x;
    int v = (t < nb) ? bsum[t] : 0;
    lds[t] = v;
    __syncthreads();
    for (int off = 1; off < 256; off <<= 1) {
        int xv = (t >= off) ? lds[t - off] : 0;
        __syncthreads();
        lds[t] += xv;
        __syncthreads();
    }
    if (t < nb) bsum[t] = lds[t] - v;
}

// ----------------------------------------- coarse bucket partition --------
__global__ __launch_bounds__(256) void count_bucket_kernel(
    const int* __restrict__ col, int* __restrict__ cnt,
    unsigned int* __restrict__ serp, int E, int NB, int NBK, int BS)
{
    __shared__ int lc[NBKT];
    int t = threadIdx.x;
    if (blockIdx.x == 0 && t < 64) serp[t] = 0;   // fused serp init
    for (int i = t; i < NBK; i += 256) lc[i] = 0;
    __syncthreads();
    for (int s = 0; s < EPB / 256; ++s) {
        int e = blockIdx.x * EPB + s * 256 + t;
        if (e < E) atomicAdd(lc + (unsigned)col[e] / (unsigned)BS, 1);
    }
    __syncthreads();
    for (int i = t; i < NBK; i += 256)
        cnt[(size_t)i * NB + blockIdx.x] = lc[i];
}

// edata.x packs row | (local_col << 20). off final = off[idx]+bsum[idx>>10]
__global__ __launch_bounds__(256) void place_kernel(
    const int* __restrict__ row, const int* __restrict__ col,
    const float* __restrict__ ew, const int* __restrict__ off,
    const int* __restrict__ bsum,
    int2* __restrict__ edata, int E, int NB, int NBK, int BS)
{
    __shared__ int lc[NBKT];
    int t = threadIdx.x;
    for (int i = t; i < NBK; i += 256) lc[i] = 0;
    __syncthreads();
    for (int s = 0; s < EPB / 256; ++s) {
        int e = blockIdx.x * EPB + s * 256 + t;
        if (e < E) {
            int cv = col[e];
            int c = (unsigned)cv / (unsigned)BS;
            int lcol = cv - c * BS;
            int r = atomicAdd(lc + c, 1);
            int idx = c * NB + blockIdx.x;
            int pos = off[idx] + bsum[idx >> 10] + r;
            edata[pos] = make_int2(row[e] | (lcol << 20), __float_as_int(ew[e]));
        }
    }
}

// per-bucket in-place counting sort by local node; emits deg/startp.
__global__ __launch_bounds__(256) void bucket_sort_kernel(
    int2* __restrict__ edata, const int* __restrict__ off,
    const int* __restrict__ bsum,
    int* __restrict__ deg, int* __restrict__ startp,
    int NB, int BS, int N, int E, int NBK)
{
    __shared__ int hist[256];
    __shared__ int psum[256];
    int b = blockIdx.x;
    int t = threadIdx.x;
    int i0 = b * NB;
    int base = off[i0] + bsum[i0 >> 10];
    int end = E;
    if (b + 1 < NBK) {
        int i1 = (b + 1) * NB;
        end = off[i1] + bsum[i1 >> 10];
    }
    int cnt = end - base;
    int nlo = b * BS;

    hist[t] = 0;
    __syncthreads();

    int2 regs[8];
    int lnode[8];
#pragma unroll
    for (int ii = 0; ii < 8; ++ii) {
        int i = t + ii * 256;
        if (i < cnt) {
            regs[ii] = edata[base + i];
            lnode[ii] = ((unsigned)regs[ii].x) >> 20;
            atomicAdd(hist + lnode[ii], 1);   // no-return ds_add
        }
    }
    __syncthreads();

    int cv = hist[t];
    psum[t] = cv;
    __syncthreads();
    for (int o = 1; o < 256; o <<= 1) {
        int xv = (t >= o) ? psum[t - o] : 0;
        __syncthreads();
        psum[t] += xv;
        __syncthreads();
    }
    int excl = psum[t] - cv;
    int ng = nlo + t;
    if (t < BS && ng < N) {
        deg[ng] = cv;
        startp[ng] = base + excl;
    }
    hist[t] = excl;
    __syncthreads();

#pragma unroll
    for (int ii = 0; ii < 8; ++ii) {
        int i = t + ii * 256;
        if (i < cnt) {
            int pos = atomicAdd(hist + lnode[ii], 1);
            edata[base + pos] = make_int2(regs[ii].x & 0xFFFFF, regs[ii].y);
        }
    }
}

// ----------------------------------------------- fused embed + UV (L0) ----
// R27: embed as K=32-padded MFMA from f16-cast nf, then hlds roundtrip ->
// layer-0 UV production (same epilogue as update_mfma). Writes xh + UV.
// Deletes the standalone embed kernel + uv_mfma launch + 12.8 MB re-read.
__global__ __launch_bounds__(64, 2) void embed_uv_kernel(
    const float* __restrict__ nf, const f16x8* __restrict__ embB,  // [4][64]
    const float* __restrict__ eb,
    const f16x8* __restrict__ uvB0,  // [24][64] layer 0
    const float* __restrict__ mb1, const float* __restrict__ ab1,
    _Float16* __restrict__ xh, _Float16* __restrict__ UV, int N)
{
    __shared__ __align__(16) _Float16 hlds[16 * 80];
    int lane = threadIdx.x;
    int wid = blockIdx.x;
    int quad = lane >> 4, l15 = lane & 15;
    int nbase = wid * 64;
    if (nbase >= N) return;

    f16x8 Be[4];
#pragma unroll
    for (int i = 0; i < 4; ++i) Be[i] = embB[i * 64 + lane];
    f16x8 B[24];
#pragma unroll
    for (int i = 0; i < 24; ++i) B[i] = uvB0[i * 64 + lane];
    float bve[4];
#pragma unroll
    for (int nt = 0; nt < 4; ++nt) bve[nt] = eb[nt * 16 + l15];
    float bvn[12];
#pragma unroll
    for (int q = 0; q < 12; ++q) {
        int sd = q / 6, nt2 = q % 6;
        int col = nt2 * 16 + l15;
        bvn[q] = sd ? 0.f : (col < 64 ? mb1[col] : ab1[col - 64]);
    }

    for (int mt = 0; mt < 4; ++mt) {
        int na = nbase + mt * 16 + l15;
        if (na >= N) na = N - 1;
        // A-frag from nf (K=32 padded, only k<18 nonzero)
        f16x8 Ax;
#pragma unroll
        for (int j = 0; j < 8; ++j) {
            int k = quad * 8 + j;
            Ax[j] = (k < F) ? (_Float16)nf[(size_t)na * F + k] : (_Float16)0;
        }

        f32x4 C[4];
#pragma unroll
        for (int nt = 0; nt < 4; ++nt) {
            f32x4 cc = {bve[nt], bve[nt], bve[nt], bve[nt]};
            cc = __builtin_amdgcn_mfma_f32_16x16x32_f16(Ax, Be[nt], cc, 0, 0, 0);
            C[nt] = cc;
        }

        int noder = nbase + mt * 16 + quad * 4;
        float xn[4][4];
#pragma unroll
        for (int r = 0; r < 4; ++r) {
            int ng = noder + r;
#pragma unroll
            for (int nt = 0; nt < 4; ++nt) {
                float v = fmaxf(C[nt][r], 0.f);
                xn[nt][r] = v;
                if (ng < N) xh[(size_t)ng * H + nt * 16 + l15] = (_Float16)v;
            }
        }

        // hlds roundtrip -> A2 frags -> UV
#pragma unroll
        for (int nt = 0; nt < 4; ++nt)
#pragma unroll
            for (int r = 0; r < 4; ++r)
                hlds[(quad * 4 + r) * 80 + nt * 16 + l15] = (_Float16)xn[nt][r];
        __asm__ __volatile__("s_waitcnt lgkmcnt(0)" ::: "memory");
        f16x8 A2[2];
        A2[0] = *(const f16x8*)&hlds[l15 * 80 + quad * 8];
        A2[1] = *(const f16x8*)&hlds[l15 * 80 + 32 + quad * 8];
        __asm__ __volatile__("s_waitcnt lgkmcnt(0)" ::: "memory");

#pragma unroll
        for (int q = 0; q < 12; ++q) {
            int sd = q / 6, nt2 = q % 6;
            f32x4 cc = {bvn[q], bvn[q], bvn[q], bvn[q]};
            cc = __builtin_amdgcn_mfma_f32_16x16x32_f16(A2[0], B[sd * 12 + nt2 * 2], cc, 0, 0, 0);
            cc = __builtin_amdgcn_mfma_f32_16x16x32_f16(A2[1], B[sd * 12 + nt2 * 2 + 1], cc, 0, 0, 0);
#pragma unroll
            for (int r = 0; r < 4; ++r) {
                int n = noder + r;
                if (n < N)
                    UV[(size_t)n * 192 + sd * 96 + nt2 * 16 + l15] = (_Float16)cc[r];
            }
        }
    }
}

// ---------------------------------------------------------- edge gather ---
// Unchanged from R26 (memory-system-bound; control for this round).
__global__ __launch_bounds__(256) void edge_gather_kernel(
    const _Float16* __restrict__ UV,   // [N][192]: U 0..95, V 96..191
    const int2* __restrict__ edata,    // CSR-sorted {row, ew}
    const int* __restrict__ startp, const int* __restrict__ deg,
    const float* __restrict__ aW2, const float* __restrict__ ab2,
    _Float16* __restrict__ aggN, float* __restrict__ snorm, int N)
{
    int wid = (blockIdx.x * 256 + threadIdx.x) >> 6;
    int lane = threadIdx.x & 63;
    int g = lane >> 3, s = lane & 7;
    int n0 = wid * NPW;
    if (n0 >= N) return;
    int n1 = n0 + NPW; if (n1 > N) n1 = N;

    float aw2v[4];
#pragma unroll
    for (int j = 0; j < 4; ++j) aw2v[j] = aW2[s * 4 + j];
#if __has_builtin(__builtin_amdgcn_fdot2)
    h16x2 aw01, aw23;
    aw01[0] = (__fp16)aw2v[0]; aw01[1] = (__fp16)aw2v[1];
    aw23[0] = (__fp16)aw2v[2]; aw23[1] = (__fp16)aw2v[3];
#endif
    float ab2v = ab2[0];
    const f16x2 zer = {(_Float16)0, (_Float16)0};

    typedef union { f16x8 v; f16x2 p[4]; } u8p;
    typedef union { f16x4 v; f16x2 p[2]; h16x2 h[2]; } u4p;

    for (int n = n0; n < n1; ++n) {
        int e0 = startp[n];
        int d = deg[n];
        int iters = (d + 7) >> 3;
        const _Float16* vrow = UV + (size_t)n * 192 + 96;
        u8p vm; vm.v = *(const f16x8*)(vrow + s * 8);
        u4p va; va.v = *(const f16x4*)(vrow + 64 + s * 4);

        float acc[8];
#pragma unroll
        for (int j = 0; j < 8; ++j) acc[j] = 0.f;
        float rfw = 0.f;

        if (iters > 0) {
            int2 ed0, ed1 = {0, 0}, ed2 = {0, 0};
            u8p um0;
            u4p ua0;
            {
                int ei = g;
                ed0 = edata[e0 + (ei < d ? ei : 0)];
                const _Float16* ur = UV + (size_t)ed0.x * 192;
                um0.v = *(const f16x8*)(ur + s * 8);
                ua0.v = *(const f16x4*)(ur + 64 + s * 4);
            }
            if (iters > 1) {
                int ei = 8 + g;
                ed1 = edata[e0 + (ei < d ? ei : 0)];
            }
            for (int it = 0; it < iters; ++it) {
                u8p umn = um0;
                u4p uan = ua0;
                if (it + 1 < iters) {
                    const _Float16* ur = UV + (size_t)ed1.x * 192;
                    umn.v = *(const f16x8*)(ur + s * 8);
                    uan.v = *(const f16x4*)(ur + 64 + s * 4);
                }
                if (it + 2 < iters) {
                    int ei = (it + 2) * 8 + g;
                    ed2 = edata[e0 + (ei < d ? ei : 0)];
                }

                int ei = it * 8 + g;
                float ew = (ei < d) ? __int_as_float(ed0.y) : 0.f;
                f16x2 za0 = __builtin_elementwise_max(ua0.p[0] + va.p[0], zer);
                f16x2 za1 = __builtin_elementwise_max(ua0.p[1] + va.p[1], zer);
#if __has_builtin(__builtin_amdgcn_fdot2)
                h16x2 hz0, hz1;
                __builtin_memcpy(&hz0, &za0, 4);
                __builtin_memcpy(&hz1, &za1, 4);
                float pp = __builtin_amdgcn_fdot2(
                    hz0, aw01,
                    __builtin_amdgcn_fdot2(hz1, aw23, 0.f, false), false);
#else
                float pp = (float)za0[0] * aw2v[0] + (float)za0[1] * aw2v[1]
                         + (float)za1[0] * aw2v[2] + (float)za1[1] * aw2v[3];
#endif
                pp += __int_as_float(__builtin_amdgcn_update_dpp(
                    0, __float_as_int(pp), 0xB1, 0xF, 0xF, true));
                pp += __int_as_float(__builtin_amdgcn_update_dpp(
                    0, __float_as_int(pp), 0x4E, 0xF, 0xF, true));
                pp += __shfl_xor(pp, 4);
                float fw = ew * __builtin_amdgcn_rcpf(1.f + __expf(-(pp + ab2v)));
#pragma unroll
                for (int j = 0; j < 4; ++j) {
                    f16x2 z = __builtin_elementwise_max(um0.p[j] + vm.p[j], zer);
                    acc[2 * j]     += (float)z[0] * fw;
                    acc[2 * j + 1] += (float)z[1] * fw;
                }
                rfw += fw;

                ed0 = ed1; ed1 = ed2; um0 = umn; ua0 = uan;
            }
        }

#pragma unroll
        for (int o = 8; o <= 32; o <<= 1) {
#pragma unroll
            for (int j = 0; j < 8; ++j) acc[j] += __shfl_xor(acc[j], o);
            rfw += __shfl_xor(rfw, o);
        }
        float inv = 1.f / fmaxf(rfw, 1e-6f);
        if (g == 0) {
            union { _Float16 h[8]; uint4 v; } O;
#pragma unroll
            for (int j = 0; j < 8; ++j) O.h[j] = (_Float16)(acc[j] * inv);
            *(uint4*)(aggN + (size_t)n * H + s * 8) = O.v;
        }
        if (lane == 0) snorm[n] = rfw * inv;
    }
}

// --------------------------------------------------------------- update ----
// 1-wave blocks; fused epilogues (UV for next layer / feature-max).
__global__ __launch_bounds__(64, 2) void update_mfma_kernel(
    _Float16* __restrict__ xh, const _Float16* __restrict__ agg,
    const float* __restrict__ snorm,
    const f16x8* __restrict__ Bfrag,  // [24][64] this layer
    const float* __restrict__ mbu,    // [64]
    const float* __restrict__ ub1, const float* __restrict__ ub2,
    const f16x8* __restrict__ uvBn,   // [24][64] next layer or null
    const float* __restrict__ mb1n, const float* __restrict__ ab1n,
    _Float16* __restrict__ UV,        // out if uvBn
    unsigned int* __restrict__ serp,  // out if doMax
    int N, int doMax)
{
    __shared__ __align__(16) _Float16 hlds[16 * 80];
    int lane = threadIdx.x;
    int wid = blockIdx.x;
    int quad = lane >> 4, l15 = lane & 15;
    int nbase = wid * 64;
    if (nbase >= N) return;

    f16x8 Bu[8], Bm[8], Bw[8];
#pragma unroll
    for (int i = 0; i < 8; ++i) {
        Bu[i] = Bfrag[i * 64 + lane];
        Bm[i] = Bfrag[(8 + i) * 64 + lane];
        Bw[i] = Bfrag[(16 + i) * 64 + lane];
    }
    float mbuv[4], b1v[4], b2v[4];
#pragma unroll
    for (int nt = 0; nt < 4; ++nt) {
        mbuv[nt] = mbu[nt * 16 + l15];
        b1v[nt] = ub1[nt * 16 + l15];
        b2v[nt] = ub2[nt * 16 + l15];
    }
    float bvn[12];
    if (uvBn) {
#pragma unroll
        for (int q = 0; q < 12; ++q) {
            int sd = q / 6, nt2 = q % 6;
            int col = nt2 * 16 + l15;
            bvn[q] = sd ? 0.f : (col < 64 ? mb1n[col] : ab1n[col - 64]);
        }
    }
    float lmax[4] = {0.f, 0.f, 0.f, 0.f};

    for (int mt = 0; mt < 4; ++mt) {
        int na = nbase + mt * 16 + l15;
        if (na >= N) na = N - 1;
        const f16x8* xrow = (const f16x8*)(xh + (size_t)na * H);
        f16x8 Ax[2];
        Ax[0] = xrow[quad];
        Ax[1] = xrow[4 + quad];
        const f16x8* arow = (const f16x8*)(agg + (size_t)na * H);
        f16x8 Aa[2];
        Aa[0] = arow[quad];
        Aa[1] = arow[4 + quad];

        f32x4 Cx[4], Ca[4];
#pragma unroll
        for (int nt = 0; nt < 4; ++nt) {
            f32x4 cx = {0.f, 0.f, 0.f, 0.f}, ca = {0.f, 0.f, 0.f, 0.f};
#pragma unroll
            for (int kk = 0; kk < 2; ++kk) {
                cx = __builtin_amdgcn_mfma_f32_16x16x32_f16(Ax[kk], Bu[nt * 2 + kk], cx, 0, 0, 0);
                ca = __builtin_amdgcn_mfma_f32_16x16x32_f16(Aa[kk], Bm[nt * 2 + kk], ca, 0, 0, 0);
            }
            Cx[nt] = cx; Ca[nt] = ca;
        }

        int noder = nbase + mt * 16 + quad * 4;
        float sn_r[4];
#pragma unroll
        for (int r = 0; r < 4; ++r) {
            int ng = noder + r; if (ng >= N) ng = N - 1;
            sn_r[r] = snorm[ng];
        }

#pragma unroll
        for (int nt = 0; nt < 4; ++nt) {
#pragma unroll
            for (int r = 0; r < 4; ++r) {
                float hv = fmaxf(Cx[nt][r] + Ca[nt][r]
                                 + sn_r[r] * mbuv[nt] + b1v[nt], 0.f);
                hlds[(quad * 4 + r) * 80 + nt * 16 + l15] = (_Float16)hv;
            }
        }
        __asm__ __volatile__("s_waitcnt lgkmcnt(0)" ::: "memory");
        f16x8 Ah[2];
        Ah[0] = *(const f16x8*)&hlds[l15 * 80 + quad * 8];
        Ah[1] = *(const f16x8*)&hlds[l15 * 80 + 32 + quad * 8];
        __asm__ __volatile__("s_waitcnt lgkmcnt(0)" ::: "memory");

        f32x4 C2[4];
#pragma unroll
        for (int nt = 0; nt < 4; ++nt) {
            f32x4 cc = {0.f, 0.f, 0.f, 0.f};
#pragma unroll
            for (int kk = 0; kk < 2; ++kk)
                cc = __builtin_amdgcn_mfma_f32_16x16x32_f16(Ah[kk], Bw[nt * 2 + kk], cc, 0, 0, 0);
            C2[nt] = cc;
        }

        // ---- xnew + xh write (+ local max) ----
        float xn[4][4];
#pragma unroll
        for (int r = 0; r < 4; ++r) {
            int ng = noder + r;
            if (ng < N) {
#pragma unroll
                for (int nt = 0; nt < 4; ++nt) {
                    size_t idx = (size_t)ng * H + nt * 16 + l15;
                    float xo = (float)xh[idx];
                    float v = fmaxf(C2[nt][r] + b2v[nt] + xo, 0.f);
                    xn[nt][r] = v;
                    xh[idx] = (_Float16)v;
                }
            } else {
#pragma unroll
                for (int nt = 0; nt < 4; ++nt) xn[nt][r] = 0.f;
            }
        }
        if (doMax) {
#pragma unroll
            for (int nt = 0; nt < 4; ++nt)
#pragma unroll
                for (int r = 0; r < 4; ++r) lmax[nt] = fmaxf(lmax[nt], xn[nt][r]);
        }

        // ---- fused UV production for next layer ----
        if (uvBn) {
#pragma unroll
            for (int nt = 0; nt < 4; ++nt)
#pragma unroll
                for (int r = 0; r < 4; ++r)
                    hlds[(quad * 4 + r) * 80 + nt * 16 + l15] = (_Float16)xn[nt][r];
            __asm__ __volatile__("s_waitcnt lgkmcnt(0)" ::: "memory");
            f16x8 A2[2];
            A2[0] = *(const f16x8*)&hlds[l15 * 80 + quad * 8];
            A2[1] = *(const f16x8*)&hlds[l15 * 80 + 32 + quad * 8];
            __asm__ __volatile__("s_waitcnt lgkmcnt(0)" ::: "memory");

#pragma unroll
            for (int q = 0; q < 12; ++q) {
                int sd = q / 6, nt2 = q % 6;
                f16x8 Ba = uvBn[(sd * 12 + nt2 * 2) * 64 + lane];
                f16x8 Bb = uvBn[(sd * 12 + nt2 * 2 + 1) * 64 + lane];
                f32x4 cc = {bvn[q], bvn[q], bvn[q], bvn[q]};
                cc = __builtin_amdgcn_mfma_f32_16x16x32_f16(A2[0], Ba, cc, 0, 0, 0);
                cc = __builtin_amdgcn_mfma_f32_16x16x32_f16(A2[1], Bb, cc, 0, 0, 0);
#pragma unroll
                for (int r = 0; r < 4; ++r) {
                    int n = noder + r;
                    if (n < N)
                        UV[(size_t)n * 192 + sd * 96 + nt2 * 16 + l15] = (_Float16)cc[r];
                }
            }
        }
    }

    if (doMax) {
#pragma unroll
        for (int nt = 0; nt < 4; ++nt) {
            float m = lmax[nt];
            m = fmaxf(m, __shfl_xor(m, 16));
            m = fmaxf(m, __shfl_xor(m, 32));
            if (quad == 0) atomicMax(serp + nt * 16 + l15, __float_as_uint(m));
        }
    }
}

// ----------------------------------------------------------------- head ----
__global__ void head_kernel(const unsigned int* __restrict__ serp,
                            const float* __restrict__ hW,
                            const float* __restrict__ hb,
                            float* __restrict__ out)
{
    int j = threadIdx.x;  // 64 threads = 1 wave
    float v = __uint_as_float(serp[j]) * hW[j];
#pragma unroll
    for (int off = 32; off > 0; off >>= 1) v += __shfl_down(v, off);
    if (j == 0) out[0] = v + hb[0];
}

// --------------------------------------------------------------- launch ----
extern "C" void kernel_launch(void* const* d_in, const int* in_sizes, int n_in,
                              void* d_out, int out_size, void* d_ws, size_t ws_size,
                              hipStream_t stream)
{
    const float* nf  = (const float*)d_in[0];
    const int*   ei  = (const int*)d_in[1];
    const float* ew  = (const float*)d_in[2];
    const float* eW  = (const float*)d_in[3];
    const float* eb_ = (const float*)d_in[4];
    const float* mW1 = (const float*)d_in[5];
    const float* mb1 = (const float*)d_in[6];
    const float* mW2 = (const float*)d_in[7];
    const float* mb2 = (const float*)d_in[8];
    const float* aW1 = (const float*)d_in[9];
    const float* ab1 = (const float*)d_in[10];
    const float* aW2 = (const float*)d_in[11];
    const float* ab2 = (const float*)d_in[12];
    const float* uW1 = (const float*)d_in[13];
    const float* ub1 = (const float*)d_in[14];
    const float* uW2 = (const float*)d_in[15];
    const float* ub2 = (const float*)d_in[16];
    const float* hW  = (const float*)d_in[17];
    const float* hb  = (const float*)d_in[18];

    int N = in_sizes[0] / F;
    int E = in_sizes[2];
    const int* row = ei;
    const int* col = ei + E;

    size_t Nr = ((size_t)N + 3) & ~(size_t)3;
    size_t Er = ((size_t)E + 3) & ~(size_t)3;

    int BS  = (N + NBKT - 1) / NBKT;       // nodes per bucket (<=256)
    int NBK = (N + BS - 1) / BS;           // actual buckets (<=NBKT)
    int NB  = (E + EPB - 1) / EPB;         // blocks in count/place
    size_t M  = (size_t)NBK * NB;
    size_t Mr = (M + 3) & ~(size_t)3;

    _Float16* xh   = (_Float16*)d_ws;                 // Nr*64 f16
    _Float16* aggN = xh + Nr * 64;                    // Nr*64 f16
    float* snorm   = (float*)(aggN + Nr * 64);        // Nr
    unsigned int* serp = (unsigned int*)(snorm + Nr); // 64
    int* deg       = (int*)(serp + 64);               // Nr
    int* startp    = deg + Nr;                        // Nr
    int* bsum      = startp + Nr;                     // 256
    float* M2U     = (float*)(bsum + 256);            // 8192
    float* mbu     = M2U + 8192;                      // 128
    f16x8* updB    = (f16x8*)(mbu + 128);             // 3072 units
    f16x8* uvB     = updB + 3072;                     // 3072 units
    f16x8* embB    = uvB + 3072;                      // 256 units
    _Float16* UV   = (_Float16*)(embB + 256);         // Nr*192
    int* cnt       = (int*)(UV + Nr * 192);           // Mr
    int* off       = cnt + Mr;                        // Mr
    int2* edata    = (int2*)(off + Mr);               // Er

    int nbA = (int)((M + 1023) / 1024);               // <=256

    count_bucket_kernel<<<NB, 256, 0, stream>>>(col, cnt, serp, E, NB, NBK, BS);
    scan1_kernel<<<nbA, 256, 0, stream>>>(cnt, off, bsum, (int)M);
    scan2_kernel<<<1, 256, 0, stream>>>(bsum, nbA);
    place_kernel<<<NB, 256, 0, stream>>>(row, col, ew, off, bsum, edata, E, NB, NBK, BS);
    bucket_sort_kernel<<<NBK, 256, 0, stream>>>(edata, off, bsum, deg, startp,
                                                NB, BS, N, E, NBK);

    prep_update_kernel<<<32, 256, 0, stream>>>(mW2, mb2, uW1, M2U, mbu);
    packfrag_all_kernel<<<25, 256, 0, stream>>>(mW1, aW1, uW1, M2U, uW2, eW,
                                                uvB, updB, embB);

    int nwaves_n = (N + 63) / 64;
    int nb_eg = (N + NPW * 4 - 1) / (NPW * 4);

    // fused embed + layer-0 UV
    embed_uv_kernel<<<nwaves_n, 64, 0, stream>>>(
        nf, embB, eb_, uvB, mb1, ab1, xh, UV, N);
    edge_gather_kernel<<<nb_eg, 256, 0, stream>>>(
        UV, edata, startp, deg, aW2, ab2, aggN, snorm, N);
    // layer-0 update, fused production of layer-1 UV
    update_mfma_kernel<<<nwaves_n, 64, 0, stream>>>(
        xh, aggN, snorm, updB, mbu, ub1, ub2,
        uvB + 24 * 64, mb1 + H, ab1 + (H / 2), UV, nullptr, N, 0);
    edge_gather_kernel<<<nb_eg, 256, 0, stream>>>(
        UV, edata, startp, deg, aW2 + (H / 2), ab2 + 1, aggN, snorm, N);
    // layer-1 update, fused feature-max
    update_mfma_kernel<<<nwaves_n, 64, 0, stream>>>(
        xh, aggN, snorm, updB + 24 * 64, mbu + 64, ub1 + H, ub2 + H,
        nullptr, nullptr, nullptr, nullptr, serp, N, 1);

    head_kernel<<<1, 64, 0, stream>>>(serp, hW, hb, (float*)d_out);
}